// Round 6
// baseline (1201.410 us; speedup 1.0000x reference)
//
#include <hip/hip_runtime.h>
#include <cstdint>
#include <cstddef>

#define BB 8
#define CC 64
#define NN 4096
#define OO 64
#define KK 20
#define TWO_C 128

#define LCH 512    // j-chunk length for knn
#define NCH 8      // number of j-chunks

typedef float vf4 __attribute__((ext_vector_type(4)));

// ---------------- kernel 0: transpose x[B,C,N] -> xT[B,N,C] ----------------
__global__ __launch_bounds__(256) void transpose_kernel(const float* __restrict__ x,
                                                        float* __restrict__ xT) {
    __shared__ float t[64][65];
    const int b = blockIdx.y;
    const int n0 = blockIdx.x * 64;
    const int ln = threadIdx.x & 63, g = threadIdx.x >> 6;
#pragma unroll
    for (int i = 0; i < 16; ++i) {
        int c = g * 16 + i;
        t[c][ln] = x[((size_t)b * CC + c) * NN + n0 + ln];
    }
    __syncthreads();
#pragma unroll
    for (int i = 0; i < 16; ++i) {
        int nl = g * 16 + i;
        xT[((size_t)b * NN + n0 + nl) * CC + ln] = t[ln][nl];
    }
}

// ---------------- kernel 1: squared norms xx[b,n] ----------------
__global__ __launch_bounds__(256) void xx_kernel(const float* __restrict__ x,
                                                 float* __restrict__ xx) {
    int t = blockIdx.x * 256 + threadIdx.x;  // [0, B*N)
    int b = t >> 12, n = t & (NN - 1);
    const float* xp = x + (size_t)b * CC * NN + n;
    float acc = 0.f;
#pragma unroll
    for (int c = 0; c < CC; ++c) {
        float v = xp[(size_t)c * NN];
        acc += v * v;
    }
    xx[t] = acc;
}

// Monotone float->uint map: a > b (float) <=> mu(a) > mu(b) (uint)
__device__ __forceinline__ unsigned int fmap(float d) {
    unsigned int s = __float_as_uint(d);
    return s ^ (unsigned int)(((int)s >> 31) | 0x80000000);
}

// ---------------- kernel 2a: kNN chunk pass (JT=4 j-group) ----------------
// Thread-per-row; j wave-uniform -> xj via scalar loads. JT=4 amortizes the
// xi reloads (compiler refuses to keep xi resident — rounds 2-4) over 4 j's.
// Insert is UNCONDITIONAL: round 5's guarded insert made L[] "cold" to the
// spill heuristic -> 40 VGPRs of keys went to scratch (WRITE_SIZE 10->22.6 MB,
// VGPR=64). p(any-lane-hit)~1 anyway, and a non-qualifying key falls through
// the chain leaving L unchanged, so the guard bought nothing.
// Key = (fmap(d) << 32) | ~j  -> value desc, index asc tie-break (lax.top_k).
// d-expression is bit-identical to the merge kernel's.
__global__ __launch_bounds__(256, 4) void knn_chunk_kernel(const float* __restrict__ x,
                                                           const float* __restrict__ xT,
                                                           const float* __restrict__ xx,
                                                           unsigned short* __restrict__ cand) {
    const int b = blockIdx.z;
    const int i = blockIdx.x * 256 + threadIdx.x;
    const int j0 = blockIdx.y * LCH;

    const float* xb  = x + (size_t)b * CC * NN;   // x[c][n] column layout
    const float* xTb = xT + (size_t)b * NN * CC;  // xT[n][c] row layout
    const float* xxb = xx + b * NN;

    unsigned long long L[KK];
#pragma unroll
    for (int s = 0; s < KK; ++s) L[s] = 0ull;

    for (int t = 0; t < LCH; t += 4) {
        const int jj = __builtin_amdgcn_readfirstlane(j0 + t);
        const float* xj0 = xTb + (size_t)(jj + 0) * CC;  // uniform -> s_load
        const float* xj1 = xTb + (size_t)(jj + 1) * CC;
        const float* xj2 = xTb + (size_t)(jj + 2) * CC;
        const float* xj3 = xTb + (size_t)(jj + 3) * CC;

        float a[4][4];
#pragma unroll
        for (int q = 0; q < 4; ++q)
#pragma unroll
            for (int s = 0; s < 4; ++s) a[q][s] = 0.f;

#pragma unroll
        for (int c = 0; c < CC; ++c) {
            float xv = xb[(size_t)c * NN + i];   // one reload feeds 4 j's
            a[0][c & 3] = fmaf(xv, xj0[c], a[0][c & 3]);
            a[1][c & 3] = fmaf(xv, xj1[c], a[1][c & 3]);
            a[2][c & 3] = fmaf(xv, xj2[c], a[2][c & 3]);
            a[3][c & 3] = fmaf(xv, xj3[c], a[3][c & 3]);
        }

#pragma unroll
        for (int q = 0; q < 4; ++q) {
            float d = 2.f * ((a[q][0] + a[q][1]) + (a[q][2] + a[q][3])) - xxb[jj + q];
            unsigned long long p =
                ((unsigned long long)fmap(d) << 32) | (unsigned int)(~(jj + q));
#pragma unroll
            for (int s = 0; s < KK; ++s) {
                bool take = p > L[s];
                unsigned long long nl = take ? p : L[s];
                p = take ? L[s] : p;
                L[s] = nl;
            }
        }
    }

    // store top-20 neighbor indices (desc by key); j = ~low32(key), fits u16
    unsigned short* cp = cand + (((size_t)b * NN + i) * NCH + blockIdx.y) * KK;
#pragma unroll
    for (int s = 0; s < KK; ++s)
        cp[s] = (unsigned short)(~(unsigned int)L[s] & 0xFFFFu);
}

// ---------------- kernel 2b: merge NCH*20 candidates -> final top-20 ----------------
// 4 threads per row, each re-ranks 2 chunks' 40 candidates (recompute d with the
// SAME fma grouping -> bit-identical keys), then 4-list pop-max in LDS.
// Insert unconditional here too (same anti-spill rationale).
__global__ __launch_bounds__(256, 3) void knn_merge_kernel(const float* __restrict__ xT,
                                                           const float* __restrict__ xx,
                                                           const unsigned short* __restrict__ cand,
                                                           unsigned short* __restrict__ idx_out) {
    __shared__ unsigned long long sh[64][4][KK + 1];
    const int tid = threadIdx.x;
    const int sub = tid & 3, rloc = tid >> 2;
    const int r = blockIdx.x * 64 + rloc;          // [0, B*N)
    const int b = r >> 12, i = r & (NN - 1);
    const float* xTb = xT + (size_t)b * NN * CC;
    const float* xxb = xx + b * NN;

    vf4 xiv[CC / 4];
    const float* xip = xTb + (size_t)i * CC;
#pragma unroll
    for (int c4 = 0; c4 < CC / 4; ++c4) {
        const float* p = xip + 4 * c4;
        asm volatile("global_load_dwordx4 %0, %1, off" : "=v"(xiv[c4]) : "v"(p));
    }
    asm volatile("s_waitcnt vmcnt(0)" ::: "memory");

    unsigned long long L[KK];
#pragma unroll
    for (int s = 0; s < KK; ++s) L[s] = 0ull;

    const unsigned short* cp = cand + (size_t)r * (NCH * KK) + sub * (2 * KK);
    for (int q = 0; q < 2 * KK; ++q) {
        int jj = cp[q];
        const float* xj = xTb + (size_t)jj * CC;
        float a0 = 0.f, a1 = 0.f, a2 = 0.f, a3 = 0.f;
#pragma unroll
        for (int c4 = 0; c4 < CC / 4; ++c4) {
            a0 = fmaf(xiv[c4].x, xj[4 * c4 + 0], a0);
            a1 = fmaf(xiv[c4].y, xj[4 * c4 + 1], a1);
            a2 = fmaf(xiv[c4].z, xj[4 * c4 + 2], a2);
            a3 = fmaf(xiv[c4].w, xj[4 * c4 + 3], a3);
        }
        float d = 2.f * ((a0 + a1) + (a2 + a3)) - xxb[jj];
        unsigned long long p = ((unsigned long long)fmap(d) << 32) | (unsigned int)(~jj);
#pragma unroll
        for (int s = 0; s < KK; ++s) {
            bool take = p > L[s];
            unsigned long long nl = take ? p : L[s];
            p = take ? L[s] : p;
            L[s] = nl;
        }
    }

#pragma unroll
    for (int s = 0; s < KK; ++s) sh[rloc][sub][s] = L[s];
    sh[rloc][sub][KK] = 0ull;   // sentinel (below any real key)
    __builtin_amdgcn_wave_barrier();   // 4 row-threads are in the same wave (lockstep)

    if (sub == 0) {
        int h0 = 0, h1 = 0, h2 = 0, h3 = 0;
        unsigned short* op = idx_out + (size_t)r * KK;
        for (int k = 0; k < KK; ++k) {
            unsigned long long k0 = sh[rloc][0][h0];
            unsigned long long k1 = sh[rloc][1][h1];
            unsigned long long k2 = sh[rloc][2][h2];
            unsigned long long k3 = sh[rloc][3][h3];
            unsigned long long best = k0; int src = 0;
            if (k1 > best) { best = k1; src = 1; }
            if (k2 > best) { best = k2; src = 2; }
            if (k3 > best) { best = k3; src = 3; }
            op[k] = (unsigned short)(~(unsigned int)best & 0xFFFFu);
            h0 += (src == 0); h1 += (src == 1); h2 += (src == 2); h3 += (src == 3);
        }
    }
}

// ---------------- kernel 3: P = xt*W1^T, D = xt*(W2-W1)^T ----------------
__global__ __launch_bounds__(256) void pd_kernel(const float* __restrict__ x,
                                                 const float* __restrict__ W,
                                                 float* __restrict__ P,
                                                 float* __restrict__ Dd) {
    __shared__ float w1T[CC][32];
    __shared__ float wdT[CC][32];
    const int tid = threadIdx.x;
    const int b = blockIdx.y;
    const int o0 = blockIdx.z * 32;
    for (int e = tid; e < 32 * CC; e += 256) {
        int ol = e >> 6, c = e & 63;
        float w1 = W[(o0 + ol) * TWO_C + c];
        float w2 = W[(o0 + ol) * TWO_C + CC + c];
        w1T[c][ol] = w1;
        wdT[c][ol] = w2 - w1;
    }
    __syncthreads();
    const int n = blockIdx.x * 256 + tid;
    float accp[32], accd[32];
#pragma unroll
    for (int i = 0; i < 32; ++i) { accp[i] = 0.f; accd[i] = 0.f; }
    const float* xp = x + (size_t)b * CC * NN + n;
    for (int c = 0; c < CC; ++c) {
        float xv = xp[(size_t)c * NN];
        const float4* w1r = (const float4*)&w1T[c][0];
        const float4* wdr = (const float4*)&wdT[c][0];
#pragma unroll
        for (int g = 0; g < 8; ++g) {
            float4 aw = w1r[g]; float4 bw = wdr[g];
            accp[4*g+0] += xv * aw.x; accp[4*g+1] += xv * aw.y;
            accp[4*g+2] += xv * aw.z; accp[4*g+3] += xv * aw.w;
            accd[4*g+0] += xv * bw.x; accd[4*g+1] += xv * bw.y;
            accd[4*g+2] += xv * bw.z; accd[4*g+3] += xv * bw.w;
        }
    }
    size_t base = ((size_t)b * NN + n) * OO + o0;
#pragma unroll
    for (int g = 0; g < 8; ++g) {
        *(float4*)&P[base + 4*g]  = make_float4(accp[4*g], accp[4*g+1], accp[4*g+2], accp[4*g+3]);
        *(float4*)&Dd[base + 4*g] = make_float4(accd[4*g], accd[4*g+1], accd[4*g+2], accd[4*g+3]);
    }
}

// ---------------- kernel 4: BN batch stats (sum, sumsq) per channel ----------------
__global__ __launch_bounds__(256) void stats_kernel(const float* __restrict__ P,
                                                    const float* __restrict__ Dd,
                                                    const unsigned short* __restrict__ idx,
                                                    double* __restrict__ sums) {
    const int tid = threadIdx.x;
    const int o = tid & 63, g = tid >> 6;
    const int row0 = blockIdx.x * 128;
    double s1 = 0.0, s2 = 0.0;
    for (int i = 0; i < 32; ++i) {
        int row = row0 + g + 4 * i;
        int b = row >> 12;
        float d = Dd[(size_t)row * OO + o];
        const unsigned short* ip = idx + (size_t)row * KK;
        const float* Pb = P + ((size_t)b * NN) * OO;
#pragma unroll
        for (int k = 0; k < KK; ++k) {
            int j = ip[k];
            float y = Pb[(size_t)j * OO + o] + d;
            s1 += (double)y;
            s2 += (double)y * (double)y;
        }
    }
    __shared__ double r1[4][64];
    __shared__ double r2[4][64];
    r1[g][o] = s1; r2[g][o] = s2;
    __syncthreads();
    if (g == 0) {
        double a1 = r1[0][o] + r1[1][o] + r1[2][o] + r1[3][o];
        double a2 = r2[0][o] + r2[1][o] + r2[2][o] + r2[3][o];
        atomicAdd(&sums[o], a1);
        atomicAdd(&sums[64 + o], a2);
    }
}

// ---------------- kernel 5: finalize scale/shift ----------------
__global__ void finalize_kernel(const double* __restrict__ sums,
                                const float* __restrict__ gamma,
                                const float* __restrict__ beta,
                                float* __restrict__ ss) {
    int o = threadIdx.x;  // 64 threads
    const double cnt = (double)BB * NN * KK;
    double mean = sums[o] / cnt;
    double var = sums[64 + o] / cnt - mean * mean;
    double rs = 1.0 / sqrt(var + 1e-5);
    double sc = (double)gamma[o] * rs;
    ss[o] = (float)sc;
    ss[64 + o] = (float)((double)beta[o] - mean * sc);
}

// ---------------- kernel 6: gather + BN affine + LeakyReLU + max_k + transpose ----------------
__global__ __launch_bounds__(256) void out_kernel(const float* __restrict__ P,
                                                  const float* __restrict__ Dd,
                                                  const unsigned short* __restrict__ idx,
                                                  const float* __restrict__ ss,
                                                  float* __restrict__ out) {
    __shared__ float tile[64][65];
    const int tid = threadIdx.x;
    const int o = tid & 63, g = tid >> 6;
    const int b = blockIdx.y;
    const int n0 = blockIdx.x * 64;
    const float sc = ss[o], sh = ss[64 + o];
    const float* Pb = P + ((size_t)b * NN) * OO;
    for (int i = 0; i < 16; ++i) {
        int nl = g + 4 * i;
        int row = b * NN + n0 + nl;
        float d = Dd[(size_t)row * OO + o];
        const unsigned short* ip = idx + (size_t)row * KK;
        float mv = -__builtin_inff();
#pragma unroll
        for (int k = 0; k < KK; ++k) {
            int j = ip[k];
            float y = Pb[(size_t)j * OO + o] + d;
            float t = y * sc + sh;
            t = (t >= 0.f) ? t : 0.2f * t;
            mv = fmaxf(mv, t);
        }
        tile[nl][o] = mv;
    }
    __syncthreads();
    for (int i = 0; i < 16; ++i) {
        int oo = g + 4 * i;
        out[((size_t)b * OO + oo) * NN + n0 + o] = tile[o][oo];
    }
}

// ---------------- launch ----------------
extern "C" void kernel_launch(void* const* d_in, const int* in_sizes, int n_in,
                              void* d_out, int out_size, void* d_ws, size_t ws_size,
                              hipStream_t stream) {
    (void)in_sizes; (void)n_in; (void)out_size; (void)ws_size;
    const float* x     = (const float*)d_in[0];   // [B, C, N]
    const float* W     = (const float*)d_in[1];   // [O, 2C]
    const float* gamma = (const float*)d_in[2];   // [O]
    const float* beta  = (const float*)d_in[3];   // [O]
    float* out = (float*)d_out;                   // [B, O, N] fp32

    // Workspace (peak ~20.32 MB):
    //   xx   @ 0         131,072   (live: knn+merge)
    //   xT   @ 131,072   8,388,608 (live: knn+merge)   -> reused as P
    //   cand @ 8,519,680 10,485,760 (live: knn->merge) -> reused as D
    //   idx  @ 19,005,440 1,310,720 u16 (live: merge -> end)
    //   sums @ 20,316,160, ss @ 20,317,184
    char* ws = (char*)d_ws;
    float*          xx   = (float*)ws;
    float*          xT   = (float*)(ws + 131072);
    unsigned short* cand = (unsigned short*)(ws + 8519680);
    unsigned short* idx  = (unsigned short*)(ws + 19005440);
    float*          P    = (float*)(ws + 131072);
    float*          Dd   = (float*)(ws + 8519680);
    double*         sums = (double*)(ws + 20316160);
    float*          ss   = (float*)(ws + 20317184);

    hipMemsetAsync(sums, 0, 128 * sizeof(double), stream);
    transpose_kernel<<<dim3(NN / 64, BB), 256, 0, stream>>>(x, xT);
    xx_kernel<<<dim3(BB * NN / 256), 256, 0, stream>>>(x, xx);
    knn_chunk_kernel<<<dim3(NN / 256, NCH, BB), 256, 0, stream>>>(x, xT, xx, cand);
    knn_merge_kernel<<<dim3(BB * NN / 64), 256, 0, stream>>>(xT, xx, cand, idx);
    pd_kernel<<<dim3(NN / 256, BB, 2), 256, 0, stream>>>(x, W, P, Dd);
    stats_kernel<<<dim3(BB * NN / 128), 256, 0, stream>>>(P, Dd, idx, sums);
    finalize_kernel<<<1, 64, 0, stream>>>(sums, gamma, beta, ss);
    out_kernel<<<dim3(NN / 64, BB), 256, 0, stream>>>(P, Dd, idx, ss, out);
}

// Round 7
// 1105.339 us; speedup vs baseline: 1.0869x; 1.0869x over previous
//
#include <hip/hip_runtime.h>
#include <cstdint>
#include <cstddef>

#define BB 8
#define CC 64
#define NN 4096
#define OO 64
#define KK 20
#define TWO_C 128

#define LCH 512    // j-chunk length for knn
#define NCH 8      // number of j-chunks

typedef float vf4 __attribute__((ext_vector_type(4)));

// ---------------- kernel 0: transpose x[B,C,N] -> xT[B,N,C] ----------------
__global__ __launch_bounds__(256) void transpose_kernel(const float* __restrict__ x,
                                                        float* __restrict__ xT) {
    __shared__ float t[64][65];
    const int b = blockIdx.y;
    const int n0 = blockIdx.x * 64;
    const int ln = threadIdx.x & 63, g = threadIdx.x >> 6;
#pragma unroll
    for (int i = 0; i < 16; ++i) {
        int c = g * 16 + i;
        t[c][ln] = x[((size_t)b * CC + c) * NN + n0 + ln];
    }
    __syncthreads();
#pragma unroll
    for (int i = 0; i < 16; ++i) {
        int nl = g * 16 + i;
        xT[((size_t)b * NN + n0 + nl) * CC + ln] = t[ln][nl];
    }
}

// ---------------- kernel 1: squared norms xx[b,n] ----------------
__global__ __launch_bounds__(256) void xx_kernel(const float* __restrict__ x,
                                                 float* __restrict__ xx) {
    int t = blockIdx.x * 256 + threadIdx.x;  // [0, B*N)
    int b = t >> 12, n = t & (NN - 1);
    const float* xp = x + (size_t)b * CC * NN + n;
    float acc = 0.f;
#pragma unroll
    for (int c = 0; c < CC; ++c) {
        float v = xp[(size_t)c * NN];
        acc += v * v;
    }
    xx[t] = acc;
}

// Monotone float->uint map: a > b (float) <=> mu(a) > mu(b) (uint)
__device__ __forceinline__ unsigned int fmap(float d) {
    unsigned int s = __float_as_uint(d);
    return s ^ (unsigned int)(((int)s >> 31) | 0x80000000);
}

// ---------------- kernel 2a: kNN chunk pass (JT=4 j-group) ----------------
// Thread-per-row; j wave-uniform -> xj via scalar loads. JT=4 amortizes xi
// reloads over 4 j's. Selection: 20-slot sorted insert with SEPARATE u32 key
// and u32 idx registers — gfx950 has no v_cmp_*_u64, so round 5/6's u64 chain
// expanded to ~8 VALU/slot (~320 cyc/j); the pair chain is 5 VALU/slot.
// Tie-break (lower j wins, = lax.top_k): strict '>' + ascending-j processing
// order keeps the earlier (lower-j) element above on equal keys. Exact.
// amdgpu_waves_per_eu(4,4): pin occupancy at 4 waves/EU = 128-VGPR budget so
// the allocator stops squeezing to 64 and spilling (rounds 3-6: VGPR=64).
__global__ __attribute__((amdgpu_flat_work_group_size(256, 256), amdgpu_waves_per_eu(4, 4)))
void knn_chunk_kernel(const float* __restrict__ x,
                      const float* __restrict__ xT,
                      const float* __restrict__ xx,
                      unsigned short* __restrict__ cand) {
    const int b = blockIdx.z;
    const int i = blockIdx.x * 256 + threadIdx.x;
    const int j0 = blockIdx.y * LCH;

    const float* xb  = x + (size_t)b * CC * NN;   // x[c][n] column layout
    const float* xTb = xT + (size_t)b * NN * CC;  // xT[n][c] row layout
    const float* xxb = xx + b * NN;

    unsigned int Lk[KK];
    unsigned int Li[KK];
#pragma unroll
    for (int s = 0; s < KK; ++s) { Lk[s] = 0u; Li[s] = 0u; }

    for (int t = 0; t < LCH; t += 4) {
        const int jj = __builtin_amdgcn_readfirstlane(j0 + t);
        const float* xj0 = xTb + (size_t)(jj + 0) * CC;  // uniform -> s_load
        const float* xj1 = xTb + (size_t)(jj + 1) * CC;
        const float* xj2 = xTb + (size_t)(jj + 2) * CC;
        const float* xj3 = xTb + (size_t)(jj + 3) * CC;

        float a[4][4];
#pragma unroll
        for (int q = 0; q < 4; ++q)
#pragma unroll
            for (int s = 0; s < 4; ++s) a[q][s] = 0.f;

#pragma unroll
        for (int c = 0; c < CC; ++c) {
            float xv = xb[(size_t)c * NN + i];   // one reload feeds 4 j's
            a[0][c & 3] = fmaf(xv, xj0[c], a[0][c & 3]);
            a[1][c & 3] = fmaf(xv, xj1[c], a[1][c & 3]);
            a[2][c & 3] = fmaf(xv, xj2[c], a[2][c & 3]);
            a[3][c & 3] = fmaf(xv, xj3[c], a[3][c & 3]);
        }

#pragma unroll
        for (int q = 0; q < 4; ++q) {
            float d = 2.f * ((a[q][0] + a[q][1]) + (a[q][2] + a[q][3])) - xxb[jj + q];
            unsigned int key = fmap(d);
            unsigned int id  = (unsigned int)(jj + q);
            // unconditional sorted insert (guarded version made L "cold" ->
            // scratch spill, round 5); non-qualifying keys fall through.
#pragma unroll
            for (int s = 0; s < KK; ++s) {
                bool take = key > Lk[s];
                unsigned int nk = take ? key : Lk[s];
                unsigned int ni = take ? id  : Li[s];
                key = take ? Lk[s] : key;
                id  = take ? Li[s] : id;
                Lk[s] = nk; Li[s] = ni;
            }
        }
    }

    unsigned short* cp = cand + (((size_t)b * NN + i) * NCH + blockIdx.y) * KK;
#pragma unroll
    for (int s = 0; s < KK; ++s)
        cp[s] = (unsigned short)Li[s];
}

// ---------------- kernel 2b: merge NCH*20 candidates -> final top-20 ----------------
// 4 threads per row, each re-ranks 2 chunks' 40 candidates (recompute d with the
// SAME fma grouping -> bit-identical keys), then 4-list pop-max in LDS.
// Sub s owns chunks {2s, 2s+1} (ascending j), so strict-'>' everywhere keeps
// the lower-j element on equal keys.
__global__ __launch_bounds__(256, 3) void knn_merge_kernel(const float* __restrict__ xT,
                                                           const float* __restrict__ xx,
                                                           const unsigned short* __restrict__ cand,
                                                           unsigned short* __restrict__ idx_out) {
    __shared__ unsigned int   shk[64][4][KK + 1];
    __shared__ unsigned short shi[64][4][KK];
    const int tid = threadIdx.x;
    const int sub = tid & 3, rloc = tid >> 2;
    const int r = blockIdx.x * 64 + rloc;          // [0, B*N)
    const int b = r >> 12, i = r & (NN - 1);
    const float* xTb = xT + (size_t)b * NN * CC;
    const float* xxb = xx + b * NN;

    vf4 xiv[CC / 4];
    const float* xip = xTb + (size_t)i * CC;
#pragma unroll
    for (int c4 = 0; c4 < CC / 4; ++c4) {
        const float* p = xip + 4 * c4;
        asm volatile("global_load_dwordx4 %0, %1, off" : "=v"(xiv[c4]) : "v"(p));
    }
    asm volatile("s_waitcnt vmcnt(0)" ::: "memory");

    unsigned int Lk[KK];
    unsigned int Li[KK];
#pragma unroll
    for (int s = 0; s < KK; ++s) { Lk[s] = 0u; Li[s] = 0u; }

    const unsigned short* cp = cand + (size_t)r * (NCH * KK) + sub * (2 * KK);
    for (int q = 0; q < 2 * KK; ++q) {
        int jj = cp[q];
        const float* xj = xTb + (size_t)jj * CC;
        float a0 = 0.f, a1 = 0.f, a2 = 0.f, a3 = 0.f;
#pragma unroll
        for (int c4 = 0; c4 < CC / 4; ++c4) {
            a0 = fmaf(xiv[c4].x, xj[4 * c4 + 0], a0);
            a1 = fmaf(xiv[c4].y, xj[4 * c4 + 1], a1);
            a2 = fmaf(xiv[c4].z, xj[4 * c4 + 2], a2);
            a3 = fmaf(xiv[c4].w, xj[4 * c4 + 3], a3);
        }
        float d = 2.f * ((a0 + a1) + (a2 + a3)) - xxb[jj];
        unsigned int key = fmap(d);
        unsigned int id  = (unsigned int)jj;
#pragma unroll
        for (int s = 0; s < KK; ++s) {
            bool take = key > Lk[s];
            unsigned int nk = take ? key : Lk[s];
            unsigned int ni = take ? id  : Li[s];
            key = take ? Lk[s] : key;
            id  = take ? Li[s] : id;
            Lk[s] = nk; Li[s] = ni;
        }
    }

#pragma unroll
    for (int s = 0; s < KK; ++s) {
        shk[rloc][sub][s] = Lk[s];
        shi[rloc][sub][s] = (unsigned short)Li[s];
    }
    shk[rloc][sub][KK] = 0u;   // sentinel (below any real key)
    __builtin_amdgcn_wave_barrier();   // 4 row-threads are in the same wave (lockstep)

    if (sub == 0) {
        int h0 = 0, h1 = 0, h2 = 0, h3 = 0;
        unsigned short* op = idx_out + (size_t)r * KK;
        for (int k = 0; k < KK; ++k) {
            unsigned int k0 = shk[rloc][0][h0];
            unsigned int k1 = shk[rloc][1][h1];
            unsigned int k2 = shk[rloc][2][h2];
            unsigned int k3 = shk[rloc][3][h3];
            unsigned int best = k0; int src = 0;
            if (k1 > best) { best = k1; src = 1; }
            if (k2 > best) { best = k2; src = 2; }
            if (k3 > best) { best = k3; src = 3; }
            int hs = (src == 0) ? h0 : (src == 1) ? h1 : (src == 2) ? h2 : h3;
            op[k] = shi[rloc][src][hs];
            h0 += (src == 0); h1 += (src == 1); h2 += (src == 2); h3 += (src == 3);
        }
    }
}

// ---------------- kernel 3: P = xt*W1^T, D = xt*(W2-W1)^T ----------------
__global__ __launch_bounds__(256) void pd_kernel(const float* __restrict__ x,
                                                 const float* __restrict__ W,
                                                 float* __restrict__ P,
                                                 float* __restrict__ Dd) {
    __shared__ float w1T[CC][32];
    __shared__ float wdT[CC][32];
    const int tid = threadIdx.x;
    const int b = blockIdx.y;
    const int o0 = blockIdx.z * 32;
    for (int e = tid; e < 32 * CC; e += 256) {
        int ol = e >> 6, c = e & 63;
        float w1 = W[(o0 + ol) * TWO_C + c];
        float w2 = W[(o0 + ol) * TWO_C + CC + c];
        w1T[c][ol] = w1;
        wdT[c][ol] = w2 - w1;
    }
    __syncthreads();
    const int n = blockIdx.x * 256 + tid;
    float accp[32], accd[32];
#pragma unroll
    for (int i = 0; i < 32; ++i) { accp[i] = 0.f; accd[i] = 0.f; }
    const float* xp = x + (size_t)b * CC * NN + n;
    for (int c = 0; c < CC; ++c) {
        float xv = xp[(size_t)c * NN];
        const float4* w1r = (const float4*)&w1T[c][0];
        const float4* wdr = (const float4*)&wdT[c][0];
#pragma unroll
        for (int g = 0; g < 8; ++g) {
            float4 aw = w1r[g]; float4 bw = wdr[g];
            accp[4*g+0] += xv * aw.x; accp[4*g+1] += xv * aw.y;
            accp[4*g+2] += xv * aw.z; accp[4*g+3] += xv * aw.w;
            accd[4*g+0] += xv * bw.x; accd[4*g+1] += xv * bw.y;
            accd[4*g+2] += xv * bw.z; accd[4*g+3] += xv * bw.w;
        }
    }
    size_t base = ((size_t)b * NN + n) * OO + o0;
#pragma unroll
    for (int g = 0; g < 8; ++g) {
        *(float4*)&P[base + 4*g]  = make_float4(accp[4*g], accp[4*g+1], accp[4*g+2], accp[4*g+3]);
        *(float4*)&Dd[base + 4*g] = make_float4(accd[4*g], accd[4*g+1], accd[4*g+2], accd[4*g+3]);
    }
}

// ---------------- kernel 4: BN batch stats -> per-block partials (no atomics) ----------------
__global__ __launch_bounds__(256) void stats_kernel(const float* __restrict__ P,
                                                    const float* __restrict__ Dd,
                                                    const unsigned short* __restrict__ idx,
                                                    double* __restrict__ partials) {
    const int tid = threadIdx.x;
    const int o = tid & 63, g = tid >> 6;
    const int row0 = blockIdx.x * 128;
    double s1 = 0.0, s2 = 0.0;
    for (int i = 0; i < 32; ++i) {
        int row = row0 + g + 4 * i;
        int b = row >> 12;
        float d = Dd[(size_t)row * OO + o];
        const unsigned short* ip = idx + (size_t)row * KK;
        const float* Pb = P + ((size_t)b * NN) * OO;
#pragma unroll
        for (int k = 0; k < KK; ++k) {
            int j = ip[k];
            float y = Pb[(size_t)j * OO + o] + d;
            s1 += (double)y;
            s2 += (double)y * (double)y;
        }
    }
    __shared__ double r1[4][64];
    __shared__ double r2[4][64];
    r1[g][o] = s1; r2[g][o] = s2;
    __syncthreads();
    if (g == 0) {
        double a1 = r1[0][o] + r1[1][o] + r1[2][o] + r1[3][o];
        double a2 = r2[0][o] + r2[1][o] + r2[2][o] + r2[3][o];
        partials[(size_t)blockIdx.x * 128 + o]      = a1;
        partials[(size_t)blockIdx.x * 128 + 64 + o] = a2;
    }
}

// ---------------- kernel 5: reduce partials + finalize scale/shift ----------------
#define NSTATB (BB * NN / 128)
__global__ void finalize_kernel(const double* __restrict__ partials,
                                const float* __restrict__ gamma,
                                const float* __restrict__ beta,
                                float* __restrict__ ss) {
    int o = threadIdx.x;  // 64 threads
    double s1 = 0.0, s2 = 0.0;
    for (int blk = 0; blk < NSTATB; ++blk) {
        s1 += partials[(size_t)blk * 128 + o];
        s2 += partials[(size_t)blk * 128 + 64 + o];
    }
    const double cnt = (double)BB * NN * KK;
    double mean = s1 / cnt;
    double var = s2 / cnt - mean * mean;
    double rs = 1.0 / sqrt(var + 1e-5);
    double sc = (double)gamma[o] * rs;
    ss[o] = (float)sc;
    ss[64 + o] = (float)((double)beta[o] - mean * sc);
}

// ---------------- kernel 6: gather + BN affine + LeakyReLU + max_k + transpose ----------------
__global__ __launch_bounds__(256) void out_kernel(const float* __restrict__ P,
                                                  const float* __restrict__ Dd,
                                                  const unsigned short* __restrict__ idx,
                                                  const float* __restrict__ ss,
                                                  float* __restrict__ out) {
    __shared__ float tile[64][65];
    const int tid = threadIdx.x;
    const int o = tid & 63, g = tid >> 6;
    const int b = blockIdx.y;
    const int n0 = blockIdx.x * 64;
    const float sc = ss[o], sh = ss[64 + o];
    const float* Pb = P + ((size_t)b * NN) * OO;
    for (int i = 0; i < 16; ++i) {
        int nl = g + 4 * i;
        int row = b * NN + n0 + nl;
        float d = Dd[(size_t)row * OO + o];
        const unsigned short* ip = idx + (size_t)row * KK;
        float mv = -__builtin_inff();
#pragma unroll
        for (int k = 0; k < KK; ++k) {
            int j = ip[k];
            float y = Pb[(size_t)j * OO + o] + d;
            float t = y * sc + sh;
            t = (t >= 0.f) ? t : 0.2f * t;
            mv = fmaxf(mv, t);
        }
        tile[nl][o] = mv;
    }
    __syncthreads();
    for (int i = 0; i < 16; ++i) {
        int oo = g + 4 * i;
        out[((size_t)b * OO + oo) * NN + n0 + o] = tile[o][oo];
    }
}

// ---------------- launch ----------------
extern "C" void kernel_launch(void* const* d_in, const int* in_sizes, int n_in,
                              void* d_out, int out_size, void* d_ws, size_t ws_size,
                              hipStream_t stream) {
    (void)in_sizes; (void)n_in; (void)out_size; (void)ws_size;
    const float* x     = (const float*)d_in[0];   // [B, C, N]
    const float* W     = (const float*)d_in[1];   // [O, 2C]
    const float* gamma = (const float*)d_in[2];   // [O]
    const float* beta  = (const float*)d_in[3];   // [O]
    float* out = (float*)d_out;                   // [B, O, N] fp32

    // Workspace (peak ~20.58 MB):
    //   xx       @ 0          131,072    (live: knn+merge)
    //   xT       @ 131,072    8,388,608  (live: knn+merge)   -> reused as P
    //   cand     @ 8,519,680  10,485,760 (live: knn->merge)  -> reused as D
    //   idx      @ 19,005,440 1,310,720  u16 (live: merge -> end)
    //   partials @ 20,316,160 262,144    (stats -> finalize)
    //   ss       @ 20,578,304 512
    char* ws = (char*)d_ws;
    float*          xx       = (float*)ws;
    float*          xT       = (float*)(ws + 131072);
    unsigned short* cand     = (unsigned short*)(ws + 8519680);
    unsigned short* idx      = (unsigned short*)(ws + 19005440);
    float*          P        = (float*)(ws + 131072);
    float*          Dd       = (float*)(ws + 8519680);
    double*         partials = (double*)(ws + 20316160);
    float*          ss       = (float*)(ws + 20578304);

    transpose_kernel<<<dim3(NN / 64, BB), 256, 0, stream>>>(x, xT);
    xx_kernel<<<dim3(BB * NN / 256), 256, 0, stream>>>(x, xx);
    knn_chunk_kernel<<<dim3(NN / 256, NCH, BB), 256, 0, stream>>>(x, xT, xx, cand);
    knn_merge_kernel<<<dim3(BB * NN / 64), 256, 0, stream>>>(xT, xx, cand, idx);
    pd_kernel<<<dim3(NN / 256, BB, 2), 256, 0, stream>>>(x, W, P, Dd);
    stats_kernel<<<dim3(BB * NN / 128), 256, 0, stream>>>(P, Dd, idx, partials);
    finalize_kernel<<<1, 64, 0, stream>>>(partials, gamma, beta, ss);
    out_kernel<<<dim3(NN / 64, BB), 256, 0, stream>>>(P, Dd, idx, ss, out);
}

// Round 8
// 944.019 us; speedup vs baseline: 1.2727x; 1.1709x over previous
//
#include <hip/hip_runtime.h>
#include <cstdint>
#include <cstddef>

#define BB 8
#define CC 64
#define NN 4096
#define OO 64
#define KK 20
#define TWO_C 128

#define LCH 512    // j-chunk length for knn
#define NCH 8      // number of j-chunks
#define CW  24     // candidates nominated per chunk (4 safety over KK=20)

typedef float vf4 __attribute__((ext_vector_type(4)));

// ---------------- kernel 0: transpose x[B,C,N] -> xT[B,N,C] ----------------
__global__ __launch_bounds__(256) void transpose_kernel(const float* __restrict__ x,
                                                        float* __restrict__ xT) {
    __shared__ float t[64][65];
    const int b = blockIdx.y;
    const int n0 = blockIdx.x * 64;
    const int ln = threadIdx.x & 63, g = threadIdx.x >> 6;
#pragma unroll
    for (int i = 0; i < 16; ++i) {
        int c = g * 16 + i;
        t[c][ln] = x[((size_t)b * CC + c) * NN + n0 + ln];
    }
    __syncthreads();
#pragma unroll
    for (int i = 0; i < 16; ++i) {
        int nl = g * 16 + i;
        xT[((size_t)b * NN + n0 + nl) * CC + ln] = t[ln][nl];
    }
}

// ---------------- kernel 1: squared norms xx[b,n] ----------------
__global__ __launch_bounds__(256) void xx_kernel(const float* __restrict__ x,
                                                 float* __restrict__ xx) {
    int t = blockIdx.x * 256 + threadIdx.x;  // [0, B*N)
    int b = t >> 12, n = t & (NN - 1);
    const float* xp = x + (size_t)b * CC * NN + n;
    float acc = 0.f;
#pragma unroll
    for (int c = 0; c < CC; ++c) {
        float v = xp[(size_t)c * NN];
        acc += v * v;
    }
    xx[t] = acc;
}

// Monotone float->uint map: a > b (float) <=> mu(a) > mu(b) (uint)
__device__ __forceinline__ unsigned int fmap(float d) {
    unsigned int s = __float_as_uint(d);
    return s ^ (unsigned int)(((int)s >> 31) | 0x80000000);
}

// ---------------- kernel 2a: kNN chunk pass (JT=4 j-group) ----------------
// CANDIDATE NOMINATION ONLY — merge re-ranks in exact fp32, so chunk keys can
// be lossy. Packed u32 key: top-20 bits of fmap(d) | (4095-j) in low 12 bits
// (quantized-tie -> lower j first). Sorted-insert on one u32 = v_max_u32 +
// v_min_u32 = 2 inst/slot (vs 5 for the round-7 pair chain), list = 24 regs
// (vs 40) -> total hot state ~60 regs fits the 64-VGPR allocation the
// compiler insists on (rounds 3-7), eliminating the scratch spill that cost
// ~125 inst/j. Top-CW=24 nominated to absorb quantization at the boundary.
__global__ __attribute__((amdgpu_flat_work_group_size(256, 256), amdgpu_waves_per_eu(4, 4)))
void knn_chunk_kernel(const float* __restrict__ x,
                      const float* __restrict__ xT,
                      const float* __restrict__ xx,
                      unsigned short* __restrict__ cand) {
    const int b = blockIdx.z;
    const int i = blockIdx.x * 256 + threadIdx.x;
    const int j0 = blockIdx.y * LCH;

    const float* xb  = x + (size_t)b * CC * NN;   // x[c][n] column layout
    const float* xTb = xT + (size_t)b * NN * CC;  // xT[n][c] row layout
    const float* xxb = xx + b * NN;

    unsigned int L[CW];
#pragma unroll
    for (int s = 0; s < CW; ++s) L[s] = 0u;

    for (int t = 0; t < LCH; t += 4) {
        const int jj = __builtin_amdgcn_readfirstlane(j0 + t);
        const float* xj0 = xTb + (size_t)(jj + 0) * CC;  // uniform -> s_load
        const float* xj1 = xTb + (size_t)(jj + 1) * CC;
        const float* xj2 = xTb + (size_t)(jj + 2) * CC;
        const float* xj3 = xTb + (size_t)(jj + 3) * CC;

        float a[4][4];
#pragma unroll
        for (int q = 0; q < 4; ++q)
#pragma unroll
            for (int s = 0; s < 4; ++s) a[q][s] = 0.f;

#pragma unroll
        for (int c = 0; c < CC; ++c) {
            float xv = xb[(size_t)c * NN + i];   // one reload feeds 4 j's
            a[0][c & 3] = fmaf(xv, xj0[c], a[0][c & 3]);
            a[1][c & 3] = fmaf(xv, xj1[c], a[1][c & 3]);
            a[2][c & 3] = fmaf(xv, xj2[c], a[2][c & 3]);
            a[3][c & 3] = fmaf(xv, xj3[c], a[3][c & 3]);
        }

#pragma unroll
        for (int q = 0; q < 4; ++q) {
            float d = 2.f * ((a[q][0] + a[q][1]) + (a[q][2] + a[q][3])) - xxb[jj + q];
            unsigned int p = (fmap(d) & 0xFFFFF000u) | (unsigned int)(4095 - (jj + q));
            // unconditional max/min sorted insert (guards -> cold -> spill, r5)
#pragma unroll
            for (int s = 0; s < CW; ++s) {
                unsigned int hi = p > L[s] ? p : L[s];
                p = p > L[s] ? L[s] : p;
                L[s] = hi;
            }
        }
    }

    unsigned short* cp = cand + (((size_t)b * NN + i) * NCH + blockIdx.y) * CW;
#pragma unroll
    for (int s = 0; s < CW; ++s)
        cp[s] = (unsigned short)(4095 - (L[s] & 0xFFFu));
}

// ---------------- kernel 2b: merge NCH*CW candidates -> final top-20 ----------------
// 4 threads per row, each re-ranks 2 chunks' 48 candidates with EXACT fp32
// keys (u32 pair chain), then 4-list pop-max in LDS. Sub s owns chunks
// {2s,2s+1} (ascending j ranges); within a chunk, quantized-tied entries are
// stored lower-j-first; strict '>' everywhere preserves lax.top_k tie order.
__global__ __launch_bounds__(256, 3) void knn_merge_kernel(const float* __restrict__ xT,
                                                           const float* __restrict__ xx,
                                                           const unsigned short* __restrict__ cand,
                                                           unsigned short* __restrict__ idx_out) {
    __shared__ unsigned int   shk[64][4][KK + 1];
    __shared__ unsigned short shi[64][4][KK];
    const int tid = threadIdx.x;
    const int sub = tid & 3, rloc = tid >> 2;
    const int r = blockIdx.x * 64 + rloc;          // [0, B*N)
    const int b = r >> 12, i = r & (NN - 1);
    const float* xTb = xT + (size_t)b * NN * CC;
    const float* xxb = xx + b * NN;

    vf4 xiv[CC / 4];
    const float* xip = xTb + (size_t)i * CC;
#pragma unroll
    for (int c4 = 0; c4 < CC / 4; ++c4) {
        const float* p = xip + 4 * c4;
        asm volatile("global_load_dwordx4 %0, %1, off" : "=v"(xiv[c4]) : "v"(p));
    }
    asm volatile("s_waitcnt vmcnt(0)" ::: "memory");

    unsigned int Lk[KK];
    unsigned int Li[KK];
#pragma unroll
    for (int s = 0; s < KK; ++s) { Lk[s] = 0u; Li[s] = 0u; }

    const unsigned short* cp = cand + (size_t)r * (NCH * CW) + sub * (2 * CW);
    for (int q = 0; q < 2 * CW; ++q) {
        int jj = cp[q];
        const float* xj = xTb + (size_t)jj * CC;
        float a0 = 0.f, a1 = 0.f, a2 = 0.f, a3 = 0.f;
#pragma unroll
        for (int c4 = 0; c4 < CC / 4; ++c4) {
            a0 = fmaf(xiv[c4].x, xj[4 * c4 + 0], a0);
            a1 = fmaf(xiv[c4].y, xj[4 * c4 + 1], a1);
            a2 = fmaf(xiv[c4].z, xj[4 * c4 + 2], a2);
            a3 = fmaf(xiv[c4].w, xj[4 * c4 + 3], a3);
        }
        float d = 2.f * ((a0 + a1) + (a2 + a3)) - xxb[jj];
        unsigned int key = fmap(d);
        unsigned int id  = (unsigned int)jj;
#pragma unroll
        for (int s = 0; s < KK; ++s) {
            bool take = key > Lk[s];
            unsigned int nk = take ? key : Lk[s];
            unsigned int ni = take ? id  : Li[s];
            key = take ? Lk[s] : key;
            id  = take ? Li[s] : id;
            Lk[s] = nk; Li[s] = ni;
        }
    }

#pragma unroll
    for (int s = 0; s < KK; ++s) {
        shk[rloc][sub][s] = Lk[s];
        shi[rloc][sub][s] = (unsigned short)Li[s];
    }
    shk[rloc][sub][KK] = 0u;   // sentinel (below any real key)
    __builtin_amdgcn_wave_barrier();   // 4 row-threads are in the same wave (lockstep)

    if (sub == 0) {
        int h0 = 0, h1 = 0, h2 = 0, h3 = 0;
        unsigned short* op = idx_out + (size_t)r * KK;
        for (int k = 0; k < KK; ++k) {
            unsigned int k0 = shk[rloc][0][h0];
            unsigned int k1 = shk[rloc][1][h1];
            unsigned int k2 = shk[rloc][2][h2];
            unsigned int k3 = shk[rloc][3][h3];
            unsigned int best = k0; int src = 0;
            if (k1 > best) { best = k1; src = 1; }
            if (k2 > best) { best = k2; src = 2; }
            if (k3 > best) { best = k3; src = 3; }
            int hs = (src == 0) ? h0 : (src == 1) ? h1 : (src == 2) ? h2 : h3;
            op[k] = shi[rloc][src][hs];
            h0 += (src == 0); h1 += (src == 1); h2 += (src == 2); h3 += (src == 3);
        }
    }
}

// ---------------- kernel 3: P = xt*W1^T, D = xt*(W2-W1)^T ----------------
__global__ __launch_bounds__(256) void pd_kernel(const float* __restrict__ x,
                                                 const float* __restrict__ W,
                                                 float* __restrict__ P,
                                                 float* __restrict__ Dd) {
    __shared__ float w1T[CC][32];
    __shared__ float wdT[CC][32];
    const int tid = threadIdx.x;
    const int b = blockIdx.y;
    const int o0 = blockIdx.z * 32;
    for (int e = tid; e < 32 * CC; e += 256) {
        int ol = e >> 6, c = e & 63;
        float w1 = W[(o0 + ol) * TWO_C + c];
        float w2 = W[(o0 + ol) * TWO_C + CC + c];
        w1T[c][ol] = w1;
        wdT[c][ol] = w2 - w1;
    }
    __syncthreads();
    const int n = blockIdx.x * 256 + tid;
    float accp[32], accd[32];
#pragma unroll
    for (int i = 0; i < 32; ++i) { accp[i] = 0.f; accd[i] = 0.f; }
    const float* xp = x + (size_t)b * CC * NN + n;
    for (int c = 0; c < CC; ++c) {
        float xv = xp[(size_t)c * NN];
        const float4* w1r = (const float4*)&w1T[c][0];
        const float4* wdr = (const float4*)&wdT[c][0];
#pragma unroll
        for (int g = 0; g < 8; ++g) {
            float4 aw = w1r[g]; float4 bw = wdr[g];
            accp[4*g+0] += xv * aw.x; accp[4*g+1] += xv * aw.y;
            accp[4*g+2] += xv * aw.z; accp[4*g+3] += xv * aw.w;
            accd[4*g+0] += xv * bw.x; accd[4*g+1] += xv * bw.y;
            accd[4*g+2] += xv * bw.z; accd[4*g+3] += xv * bw.w;
        }
    }
    size_t base = ((size_t)b * NN + n) * OO + o0;
#pragma unroll
    for (int g = 0; g < 8; ++g) {
        *(float4*)&P[base + 4*g]  = make_float4(accp[4*g], accp[4*g+1], accp[4*g+2], accp[4*g+3]);
        *(float4*)&Dd[base + 4*g] = make_float4(accd[4*g], accd[4*g+1], accd[4*g+2], accd[4*g+3]);
    }
}

// ---------------- kernel 4: BN batch stats -> per-block partials (no atomics) ----------------
__global__ __launch_bounds__(256) void stats_kernel(const float* __restrict__ P,
                                                    const float* __restrict__ Dd,
                                                    const unsigned short* __restrict__ idx,
                                                    double* __restrict__ partials) {
    const int tid = threadIdx.x;
    const int o = tid & 63, g = tid >> 6;
    const int row0 = blockIdx.x * 128;
    double s1 = 0.0, s2 = 0.0;
    for (int i = 0; i < 32; ++i) {
        int row = row0 + g + 4 * i;
        int b = row >> 12;
        float d = Dd[(size_t)row * OO + o];
        const unsigned short* ip = idx + (size_t)row * KK;
        const float* Pb = P + ((size_t)b * NN) * OO;
#pragma unroll
        for (int k = 0; k < KK; ++k) {
            int j = ip[k];
            float y = Pb[(size_t)j * OO + o] + d;
            s1 += (double)y;
            s2 += (double)y * (double)y;
        }
    }
    __shared__ double r1[4][64];
    __shared__ double r2[4][64];
    r1[g][o] = s1; r2[g][o] = s2;
    __syncthreads();
    if (g == 0) {
        double a1 = r1[0][o] + r1[1][o] + r1[2][o] + r1[3][o];
        double a2 = r2[0][o] + r2[1][o] + r2[2][o] + r2[3][o];
        partials[(size_t)blockIdx.x * 128 + o]      = a1;
        partials[(size_t)blockIdx.x * 128 + 64 + o] = a2;
    }
}

// ---------------- kernel 5: reduce partials + finalize scale/shift ----------------
#define NSTATB (BB * NN / 128)
__global__ void finalize_kernel(const double* __restrict__ partials,
                                const float* __restrict__ gamma,
                                const float* __restrict__ beta,
                                float* __restrict__ ss) {
    int o = threadIdx.x;  // 64 threads
    double s1 = 0.0, s2 = 0.0;
    for (int blk = 0; blk < NSTATB; ++blk) {
        s1 += partials[(size_t)blk * 128 + o];
        s2 += partials[(size_t)blk * 128 + 64 + o];
    }
    const double cnt = (double)BB * NN * KK;
    double mean = s1 / cnt;
    double var = s2 / cnt - mean * mean;
    double rs = 1.0 / sqrt(var + 1e-5);
    double sc = (double)gamma[o] * rs;
    ss[o] = (float)sc;
    ss[64 + o] = (float)((double)beta[o] - mean * sc);
}

// ---------------- kernel 6: gather + BN affine + LeakyReLU + max_k + transpose ----------------
__global__ __launch_bounds__(256) void out_kernel(const float* __restrict__ P,
                                                  const float* __restrict__ Dd,
                                                  const unsigned short* __restrict__ idx,
                                                  const float* __restrict__ ss,
                                                  float* __restrict__ out) {
    __shared__ float tile[64][65];
    const int tid = threadIdx.x;
    const int o = tid & 63, g = tid >> 6;
    const int b = blockIdx.y;
    const int n0 = blockIdx.x * 64;
    const float sc = ss[o], sh = ss[64 + o];
    const float* Pb = P + ((size_t)b * NN) * OO;
    for (int i = 0; i < 16; ++i) {
        int nl = g + 4 * i;
        int row = b * NN + n0 + nl;
        float d = Dd[(size_t)row * OO + o];
        const unsigned short* ip = idx + (size_t)row * KK;
        float mv = -__builtin_inff();
#pragma unroll
        for (int k = 0; k < KK; ++k) {
            int j = ip[k];
            float y = Pb[(size_t)j * OO + o] + d;
            float t = y * sc + sh;
            t = (t >= 0.f) ? t : 0.2f * t;
            mv = fmaxf(mv, t);
        }
        tile[nl][o] = mv;
    }
    __syncthreads();
    for (int i = 0; i < 16; ++i) {
        int oo = g + 4 * i;
        out[((size_t)b * OO + oo) * NN + n0 + o] = tile[o][oo];
    }
}

// ---------------- launch ----------------
extern "C" void kernel_launch(void* const* d_in, const int* in_sizes, int n_in,
                              void* d_out, int out_size, void* d_ws, size_t ws_size,
                              hipStream_t stream) {
    (void)in_sizes; (void)n_in; (void)out_size; (void)ws_size;
    const float* x     = (const float*)d_in[0];   // [B, C, N]
    const float* W     = (const float*)d_in[1];   // [O, 2C]
    const float* gamma = (const float*)d_in[2];   // [O]
    const float* beta  = (const float*)d_in[3];   // [O]
    float* out = (float*)d_out;                   // [B, O, N] fp32

    // Workspace (peak ~22.68 MB):
    //   xx       @ 0          131,072    (live: knn+merge)
    //   xT       @ 131,072    8,388,608  (live: knn+merge)  -> reused as P
    //   cand     @ 8,519,680  12,582,912 (live: knn->merge) -> head reused as D
    //   idx      @ 21,102,592 1,310,720  u16 (live: merge -> end)
    //   partials @ 22,413,312 262,144    (stats -> finalize)
    //   ss       @ 22,675,456 512
    char* ws = (char*)d_ws;
    float*          xx       = (float*)ws;
    float*          xT       = (float*)(ws + 131072);
    unsigned short* cand     = (unsigned short*)(ws + 8519680);
    unsigned short* idx      = (unsigned short*)(ws + 21102592);
    float*          P        = (float*)(ws + 131072);
    float*          Dd       = (float*)(ws + 8519680);
    double*         partials = (double*)(ws + 22413312);
    float*          ss       = (float*)(ws + 22675456);

    transpose_kernel<<<dim3(NN / 64, BB), 256, 0, stream>>>(x, xT);
    xx_kernel<<<dim3(BB * NN / 256), 256, 0, stream>>>(x, xx);
    knn_chunk_kernel<<<dim3(NN / 256, NCH, BB), 256, 0, stream>>>(x, xT, xx, cand);
    knn_merge_kernel<<<dim3(BB * NN / 64), 256, 0, stream>>>(xT, xx, cand, idx);
    pd_kernel<<<dim3(NN / 256, BB, 2), 256, 0, stream>>>(x, W, P, Dd);
    stats_kernel<<<dim3(BB * NN / 128), 256, 0, stream>>>(P, Dd, idx, partials);
    finalize_kernel<<<1, 64, 0, stream>>>(partials, gamma, beta, ss);
    out_kernel<<<dim3(NN / 64, BB), 256, 0, stream>>>(P, Dd, idx, ss, out);
}

// Round 9
// 863.360 us; speedup vs baseline: 1.3916x; 1.0934x over previous
//
#include <hip/hip_runtime.h>
#include <cstdint>
#include <cstddef>

#define BB 8
#define CC 64
#define NN 4096
#define OO 64
#define KK 20
#define TWO_C 128

#define LCH 512    // j-chunk length for knn
#define NCH 8      // number of j-chunks
#define CW  24     // candidates nominated per chunk (4 safety over KK=20)

typedef float vf4 __attribute__((ext_vector_type(4)));
typedef _Float16 hf2 __attribute__((ext_vector_type(2)));

__device__ __forceinline__ unsigned int pack_h2(float a, float b) {
    hf2 h; h.x = (_Float16)a; h.y = (_Float16)b;
    return __builtin_bit_cast(unsigned int, h);
}

// ---------------- kernel 0: transpose + f16 packing ----------------
// x[B,C,N] -> xT[B,N,C] (fp32, for exact merge re-rank)
//          -> xTh[B,N,32] packed half2 rows (chunk SMEM loads, half the bytes)
//          -> xh2[B,32,N] packed half2 columns (chunk coalesced lane loads)
__global__ __launch_bounds__(256) void transpose_kernel(const float* __restrict__ x,
                                                        float* __restrict__ xT,
                                                        unsigned int* __restrict__ xTh,
                                                        unsigned int* __restrict__ xh2) {
    __shared__ float t[64][65];
    const int b = blockIdx.y;
    const int n0 = blockIdx.x * 64;
    const int tid = threadIdx.x;
    const int ln = tid & 63, g = tid >> 6;
#pragma unroll
    for (int i = 0; i < 16; ++i) {
        int c = g * 16 + i;
        t[c][ln] = x[((size_t)b * CC + c) * NN + n0 + ln];
    }
    __syncthreads();
#pragma unroll
    for (int i = 0; i < 16; ++i) {
        int nl = g * 16 + i;
        xT[((size_t)b * NN + n0 + nl) * CC + ln] = t[ln][nl];
    }
#pragma unroll
    for (int it = 0; it < 8; ++it) {
        int e = it * 256 + tid;           // 0..2047
        int nl = e >> 5, cp = e & 31;
        xTh[((size_t)b * NN + n0 + nl) * 32 + cp] = pack_h2(t[2*cp][nl], t[2*cp+1][nl]);
    }
#pragma unroll
    for (int it = 0; it < 8; ++it) {
        int e = it * 256 + tid;
        int cp = e >> 6, n = e & 63;
        xh2[((size_t)b * 32 + cp) * NN + n0 + n] = pack_h2(t[2*cp][n], t[2*cp+1][n]);
    }
}

// ---------------- kernel 1: squared norms xx[b,n] ----------------
__global__ __launch_bounds__(256) void xx_kernel(const float* __restrict__ x,
                                                 float* __restrict__ xx) {
    int t = blockIdx.x * 256 + threadIdx.x;  // [0, B*N)
    int b = t >> 12, n = t & (NN - 1);
    const float* xp = x + (size_t)b * CC * NN + n;
    float acc = 0.f;
#pragma unroll
    for (int c = 0; c < CC; ++c) {
        float v = xp[(size_t)c * NN];
        acc += v * v;
    }
    xx[t] = acc;
}

// Monotone float->uint map: a > b (float) <=> mu(a) > mu(b) (uint)
__device__ __forceinline__ unsigned int fmap(float d) {
    unsigned int s = __float_as_uint(d);
    return s ^ (unsigned int)(((int)s >> 31) | 0x80000000);
}

// ---------------- kernel 2a: kNN chunk pass (f16 dot2, JT=4) ----------------
// NOMINATION ONLY — merge re-ranks exactly in fp32, so chunk distances can be
// f16 (v_dot2_f32_f16: 2 MAC/inst halves the fmac issue; half2 SMEM rows halve
// the s_load bytes). Error budget: f16 dot RMS ~0.016 << quant bin (~0.06) <<
// rank-24-local vs rank-20-global depth margin (~2.0 d-units, tail gaps ~0.5).
// Packed u32 key: top-20 bits of fmap(d) | (4095-j) low 12 (lower j wins on
// quantized ties). 24-reg list + max/min insert = no spill (r8: VGPR=56).
__global__ __attribute__((amdgpu_flat_work_group_size(256, 256), amdgpu_waves_per_eu(4, 4)))
void knn_chunk_kernel(const unsigned int* __restrict__ xh2,
                      const unsigned int* __restrict__ xTh,
                      const float* __restrict__ xx,
                      unsigned short* __restrict__ cand) {
    const int b = blockIdx.z;
    const int i = blockIdx.x * 256 + threadIdx.x;
    const int j0 = blockIdx.y * LCH;

    const unsigned int* xb  = xh2 + (size_t)b * 32 * NN;  // [cp][n] coalesced
    const unsigned int* xTb = xTh + (size_t)b * NN * 32;  // [n][cp] SMEM rows
    const float* xxb = xx + b * NN;

    unsigned int L[CW];
#pragma unroll
    for (int s = 0; s < CW; ++s) L[s] = 0u;

    for (int t = 0; t < LCH; t += 4) {
        const int jj = __builtin_amdgcn_readfirstlane(j0 + t);
        const unsigned int* xj0 = xTb + (size_t)(jj + 0) * 32;  // uniform -> s_load
        const unsigned int* xj1 = xTb + (size_t)(jj + 1) * 32;
        const unsigned int* xj2 = xTb + (size_t)(jj + 2) * 32;
        const unsigned int* xj3 = xTb + (size_t)(jj + 3) * 32;

        float a[4][4];
#pragma unroll
        for (int q = 0; q < 4; ++q)
#pragma unroll
            for (int s = 0; s < 4; ++s) a[q][s] = 0.f;

#pragma unroll
        for (int cp = 0; cp < 32; ++cp) {
            hf2 xv = __builtin_bit_cast(hf2, xb[(size_t)cp * NN + i]);
            a[0][cp & 3] = __builtin_amdgcn_fdot2(xv, __builtin_bit_cast(hf2, xj0[cp]), a[0][cp & 3], false);
            a[1][cp & 3] = __builtin_amdgcn_fdot2(xv, __builtin_bit_cast(hf2, xj1[cp]), a[1][cp & 3], false);
            a[2][cp & 3] = __builtin_amdgcn_fdot2(xv, __builtin_bit_cast(hf2, xj2[cp]), a[2][cp & 3], false);
            a[3][cp & 3] = __builtin_amdgcn_fdot2(xv, __builtin_bit_cast(hf2, xj3[cp]), a[3][cp & 3], false);
        }

#pragma unroll
        for (int q = 0; q < 4; ++q) {
            float d = 2.f * ((a[q][0] + a[q][1]) + (a[q][2] + a[q][3])) - xxb[jj + q];
            unsigned int p = (fmap(d) & 0xFFFFF000u) | (unsigned int)(4095 - (jj + q));
#pragma unroll
            for (int s = 0; s < CW; ++s) {
                unsigned int hi = p > L[s] ? p : L[s];
                p = p > L[s] ? L[s] : p;
                L[s] = hi;
            }
        }
    }

    unsigned short* cp = cand + (((size_t)b * NN + i) * NCH + blockIdx.y) * CW;
#pragma unroll
    for (int s = 0; s < CW; ++s)
        cp[s] = (unsigned short)(4095 - (L[s] & 0xFFFu));
}

// ---------------- kernel 2b: merge NCH*CW candidates -> final top-20 ----------------
// 4 threads per row, each re-ranks 2 chunks' 48 candidates with EXACT fp32
// keys (u32 pair chain), then 4-list pop-max in LDS. Strict '>' + ascending-j
// processing preserves lax.top_k tie order.
__global__ __launch_bounds__(256, 3) void knn_merge_kernel(const float* __restrict__ xT,
                                                           const float* __restrict__ xx,
                                                           const unsigned short* __restrict__ cand,
                                                           unsigned short* __restrict__ idx_out) {
    __shared__ unsigned int   shk[64][4][KK + 1];
    __shared__ unsigned short shi[64][4][KK];
    const int tid = threadIdx.x;
    const int sub = tid & 3, rloc = tid >> 2;
    const int r = blockIdx.x * 64 + rloc;          // [0, B*N)
    const int b = r >> 12, i = r & (NN - 1);
    const float* xTb = xT + (size_t)b * NN * CC;
    const float* xxb = xx + b * NN;

    vf4 xiv[CC / 4];
    const float* xip = xTb + (size_t)i * CC;
#pragma unroll
    for (int c4 = 0; c4 < CC / 4; ++c4) {
        const float* p = xip + 4 * c4;
        asm volatile("global_load_dwordx4 %0, %1, off" : "=v"(xiv[c4]) : "v"(p));
    }
    asm volatile("s_waitcnt vmcnt(0)" ::: "memory");

    unsigned int Lk[KK];
    unsigned int Li[KK];
#pragma unroll
    for (int s = 0; s < KK; ++s) { Lk[s] = 0u; Li[s] = 0u; }

    const unsigned short* cp = cand + (size_t)r * (NCH * CW) + sub * (2 * CW);
    for (int q = 0; q < 2 * CW; ++q) {
        int jj = cp[q];
        const float* xj = xTb + (size_t)jj * CC;
        float a0 = 0.f, a1 = 0.f, a2 = 0.f, a3 = 0.f;
#pragma unroll
        for (int c4 = 0; c4 < CC / 4; ++c4) {
            a0 = fmaf(xiv[c4].x, xj[4 * c4 + 0], a0);
            a1 = fmaf(xiv[c4].y, xj[4 * c4 + 1], a1);
            a2 = fmaf(xiv[c4].z, xj[4 * c4 + 2], a2);
            a3 = fmaf(xiv[c4].w, xj[4 * c4 + 3], a3);
        }
        float d = 2.f * ((a0 + a1) + (a2 + a3)) - xxb[jj];
        unsigned int key = fmap(d);
        unsigned int id  = (unsigned int)jj;
#pragma unroll
        for (int s = 0; s < KK; ++s) {
            bool take = key > Lk[s];
            unsigned int nk = take ? key : Lk[s];
            unsigned int ni = take ? id  : Li[s];
            key = take ? Lk[s] : key;
            id  = take ? Li[s] : id;
            Lk[s] = nk; Li[s] = ni;
        }
    }

#pragma unroll
    for (int s = 0; s < KK; ++s) {
        shk[rloc][sub][s] = Lk[s];
        shi[rloc][sub][s] = (unsigned short)Li[s];
    }
    shk[rloc][sub][KK] = 0u;   // sentinel
    __builtin_amdgcn_wave_barrier();   // 4 row-threads share a wave (lockstep)

    if (sub == 0) {
        int h0 = 0, h1 = 0, h2 = 0, h3 = 0;
        unsigned short* op = idx_out + (size_t)r * KK;
        for (int k = 0; k < KK; ++k) {
            unsigned int k0 = shk[rloc][0][h0];
            unsigned int k1 = shk[rloc][1][h1];
            unsigned int k2 = shk[rloc][2][h2];
            unsigned int k3 = shk[rloc][3][h3];
            unsigned int best = k0; int src = 0;
            if (k1 > best) { best = k1; src = 1; }
            if (k2 > best) { best = k2; src = 2; }
            if (k3 > best) { best = k3; src = 3; }
            int hs = (src == 0) ? h0 : (src == 1) ? h1 : (src == 2) ? h2 : h3;
            op[k] = shi[rloc][src][hs];
            h0 += (src == 0); h1 += (src == 1); h2 += (src == 2); h3 += (src == 3);
        }
    }
}

// ---------------- kernel 3: P = xt*W1^T, D = xt*(W2-W1)^T ----------------
__global__ __launch_bounds__(256) void pd_kernel(const float* __restrict__ x,
                                                 const float* __restrict__ W,
                                                 float* __restrict__ P,
                                                 float* __restrict__ Dd) {
    __shared__ float w1T[CC][32];
    __shared__ float wdT[CC][32];
    const int tid = threadIdx.x;
    const int b = blockIdx.y;
    const int o0 = blockIdx.z * 32;
    for (int e = tid; e < 32 * CC; e += 256) {
        int ol = e >> 6, c = e & 63;
        float w1 = W[(o0 + ol) * TWO_C + c];
        float w2 = W[(o0 + ol) * TWO_C + CC + c];
        w1T[c][ol] = w1;
        wdT[c][ol] = w2 - w1;
    }
    __syncthreads();
    const int n = blockIdx.x * 256 + tid;
    float accp[32], accd[32];
#pragma unroll
    for (int i = 0; i < 32; ++i) { accp[i] = 0.f; accd[i] = 0.f; }
    const float* xp = x + (size_t)b * CC * NN + n;
    for (int c = 0; c < CC; ++c) {
        float xv = xp[(size_t)c * NN];
        const float4* w1r = (const float4*)&w1T[c][0];
        const float4* wdr = (const float4*)&wdT[c][0];
#pragma unroll
        for (int g = 0; g < 8; ++g) {
            float4 aw = w1r[g]; float4 bw = wdr[g];
            accp[4*g+0] += xv * aw.x; accp[4*g+1] += xv * aw.y;
            accp[4*g+2] += xv * aw.z; accp[4*g+3] += xv * aw.w;
            accd[4*g+0] += xv * bw.x; accd[4*g+1] += xv * bw.y;
            accd[4*g+2] += xv * bw.z; accd[4*g+3] += xv * bw.w;
        }
    }
    size_t base = ((size_t)b * NN + n) * OO + o0;
#pragma unroll
    for (int g = 0; g < 8; ++g) {
        *(float4*)&P[base + 4*g]  = make_float4(accp[4*g], accp[4*g+1], accp[4*g+2], accp[4*g+3]);
        *(float4*)&Dd[base + 4*g] = make_float4(accd[4*g], accd[4*g+1], accd[4*g+2], accd[4*g+3]);
    }
}

// ---------------- kernel 4: BN stats -> per-block partials ----------------
// 1024 blocks x 32 rows (was 256 x 128 = 1 wave/SIMD, latency-exposed).
__global__ __launch_bounds__(256) void stats_kernel(const float* __restrict__ P,
                                                    const float* __restrict__ Dd,
                                                    const unsigned short* __restrict__ idx,
                                                    double* __restrict__ partials) {
    const int tid = threadIdx.x;
    const int o = tid & 63, g = tid >> 6;
    const int row0 = blockIdx.x * 32;
    double s1 = 0.0, s2 = 0.0;
    for (int i = 0; i < 8; ++i) {
        int row = row0 + g + 4 * i;
        int b = row >> 12;
        float d = Dd[(size_t)row * OO + o];
        const unsigned short* ip = idx + (size_t)row * KK;
        const float* Pb = P + ((size_t)b * NN) * OO;
#pragma unroll
        for (int k = 0; k < KK; ++k) {
            int j = ip[k];
            float y = Pb[(size_t)j * OO + o] + d;
            s1 += (double)y;
            s2 += (double)y * (double)y;
        }
    }
    __shared__ double r1[4][64];
    __shared__ double r2[4][64];
    r1[g][o] = s1; r2[g][o] = s2;
    __syncthreads();
    if (g == 0) {
        double a1 = r1[0][o] + r1[1][o] + r1[2][o] + r1[3][o];
        double a2 = r2[0][o] + r2[1][o] + r2[2][o] + r2[3][o];
        partials[(size_t)blockIdx.x * 128 + o]      = a1;
        partials[(size_t)blockIdx.x * 128 + 64 + o] = a2;
    }
}

// ---------------- kernel 5: reduce partials + finalize scale/shift ----------------
#define NSTATB (BB * NN / 32)
__global__ void finalize_kernel(const double* __restrict__ partials,
                                const float* __restrict__ gamma,
                                const float* __restrict__ beta,
                                float* __restrict__ ss) {
    int o = threadIdx.x;  // 64 threads
    double s1 = 0.0, s2 = 0.0;
    for (int blk = 0; blk < NSTATB; ++blk) {
        s1 += partials[(size_t)blk * 128 + o];
        s2 += partials[(size_t)blk * 128 + 64 + o];
    }
    const double cnt = (double)BB * NN * KK;
    double mean = s1 / cnt;
    double var = s2 / cnt - mean * mean;
    double rs = 1.0 / sqrt(var + 1e-5);
    double sc = (double)gamma[o] * rs;
    ss[o] = (float)sc;
    ss[64 + o] = (float)((double)beta[o] - mean * sc);
}

// ---------------- kernel 6: gather + BN affine + LeakyReLU + max_k + transpose ----------------
// 1024 blocks x 32-n tiles (was 512 x 64 = 2 waves/SIMD).
__global__ __launch_bounds__(256) void out_kernel(const float* __restrict__ P,
                                                  const float* __restrict__ Dd,
                                                  const unsigned short* __restrict__ idx,
                                                  const float* __restrict__ ss,
                                                  float* __restrict__ out) {
    __shared__ float tile[32][65];
    const int tid = threadIdx.x;
    const int o = tid & 63, g = tid >> 6;
    const int b = blockIdx.y;
    const int n0 = blockIdx.x * 32;
    const float sc = ss[o], sh = ss[64 + o];
    const float* Pb = P + ((size_t)b * NN) * OO;
    for (int i = 0; i < 8; ++i) {
        int nl = g + 4 * i;
        int row = b * NN + n0 + nl;
        float d = Dd[(size_t)row * OO + o];
        const unsigned short* ip = idx + (size_t)row * KK;
        float mv = -__builtin_inff();
#pragma unroll
        for (int k = 0; k < KK; ++k) {
            int j = ip[k];
            float y = Pb[(size_t)j * OO + o] + d;
            float t = y * sc + sh;
            t = (t >= 0.f) ? t : 0.2f * t;
            mv = fmaxf(mv, t);
        }
        tile[nl][o] = mv;
    }
    __syncthreads();
    const int nn = tid & 31, og = tid >> 5;   // 8 o-rows per pass
    for (int i = 0; i < 8; ++i) {
        int oo = og + 8 * i;
        out[((size_t)b * OO + oo) * NN + n0 + nn] = tile[nn][oo];
    }
}

// ---------------- launch ----------------
extern "C" void kernel_launch(void* const* d_in, const int* in_sizes, int n_in,
                              void* d_out, int out_size, void* d_ws, size_t ws_size,
                              hipStream_t stream) {
    (void)in_sizes; (void)n_in; (void)out_size; (void)ws_size;
    const float* x     = (const float*)d_in[0];   // [B, C, N]
    const float* W     = (const float*)d_in[1];   // [O, 2C]
    const float* gamma = (const float*)d_in[2];   // [O]
    const float* beta  = (const float*)d_in[3];   // [O]
    float* out = (float*)d_out;                   // [B, O, N] fp32

    // Workspace, phase-overlapped (peak 29.5 MB at chunk/merge):
    //   xx   @ 0           131,072   (transpose -> merge)
    //   xT   @ 131,072     8 MB      (transpose -> merge)  -> P     (pd -> end)
    //   xTh  @ 8,519,680   4 MB      (transpose -> chunk)  -> idx   (merge -> end)
    //   xh2  @ 12,713,984  4 MB      (transpose -> chunk)  -> partials+ss
    //   cand @ 16,908,288  12.58 MB  (chunk -> merge)      -> Dd    (pd -> end)
    char* ws = (char*)d_ws;
    float*          xx       = (float*)ws;
    float*          xT       = (float*)(ws + 131072);
    unsigned int*   xTh      = (unsigned int*)(ws + 8519680);
    unsigned int*   xh2      = (unsigned int*)(ws + 12713984);
    unsigned short* cand     = (unsigned short*)(ws + 16908288);
    unsigned short* idx      = (unsigned short*)(ws + 8519680);
    double*         partials = (double*)(ws + 12713984);
    float*          ss       = (float*)(ws + 13762560);
    float*          P        = (float*)(ws + 131072);
    float*          Dd       = (float*)(ws + 16908288);

    transpose_kernel<<<dim3(NN / 64, BB), 256, 0, stream>>>(x, xT, xTh, xh2);
    xx_kernel<<<dim3(BB * NN / 256), 256, 0, stream>>>(x, xx);
    knn_chunk_kernel<<<dim3(NN / 256, NCH, BB), 256, 0, stream>>>(xh2, xTh, xx, cand);
    knn_merge_kernel<<<dim3(BB * NN / 64), 256, 0, stream>>>(xT, xx, cand, idx);
    pd_kernel<<<dim3(NN / 256, BB, 2), 256, 0, stream>>>(x, W, P, Dd);
    stats_kernel<<<dim3(BB * NN / 32), 256, 0, stream>>>(P, Dd, idx, partials);
    finalize_kernel<<<1, 64, 0, stream>>>(partials, gamma, beta, ss);
    out_kernel<<<dim3(NN / 32, BB), 256, 0, stream>>>(P, Dd, idx, ss, out);
}